// Round 1
// baseline (1040.965 us; speedup 1.0000x reference)
//
#include <hip/hip_runtime.h>
#include <math.h>

#define THETA 0.7f

// Pass 1: fused 3x3 conv + vertical-diff edge conv + combine, plus per-(b,o)
// spatial-sum accumulation for the SE pooling.
// Block: one batch, 16x16 pixel tile, all 64 output channels.
// Thread: 4 output channels x (4x4 pixels) = 64 fp32 accumulators.
__global__ __launch_bounds__(256) void cdc_main_kernel(
    const float* __restrict__ x, const float* __restrict__ Wc,
    const float* __restrict__ bc, const float* __restrict__ We,
    float* __restrict__ out, float* __restrict__ sums)
{
    __shared__ float x_lds[8 * 18 * 20];   // [c_local][row(18)][stride 20]
    __shared__ float wc_lds[64 * 8 * 12];  // [o][c_local][12 (9 taps + pad)]
    __shared__ float we_lds[8 * 64];       // [c_local][o] (transposed, prescaled)

    const int tid = threadIdx.x;
    const int tileC = blockIdx.x * 16;
    const int tileR = blockIdx.y * 16;
    const int b = blockIdx.z;

    const int o0 = (tid & 15) * 4;      // 4 consecutive output channels
    const int pg = tid >> 4;            // pixel group 0..15
    const int pr = (pg >> 2) * 4;       // sub-tile row offset
    const int pc = (pg & 3) * 4;        // sub-tile col offset

    float acc[4][16];
    #pragma unroll
    for (int oo = 0; oo < 4; ++oo) {
        float init = THETA * bc[o0 + oo];   // bias folded in, prescaled
        #pragma unroll
        for (int p = 0; p < 16; ++p) acc[oo][p] = init;
    }

    for (int chunk = 0; chunk < 8; ++chunk) {
        const int c0 = chunk * 8;
        __syncthreads();   // previous iteration's compute done before restage
        // ---- stage x tile (18x18 with halo, zero-padded at borders) ----
        for (int idx = tid; idx < 8 * 18 * 18; idx += 256) {
            int c = idx / 324;
            int rem = idx - c * 324;
            int r = rem / 18;
            int col = rem - r * 18;
            int gr = tileR + r - 1;
            int gc = tileC + col - 1;
            float v = 0.f;
            if (gr >= 0 && gr < 256 && gc >= 0 && gc < 256)
                v = x[(((size_t)b * 64 + c0 + c) * 256 + gr) * 256 + gc];
            x_lds[c * 360 + r * 20 + col] = v;
        }
        // ---- stage conv weights, prescaled by theta ----
        for (int idx = tid; idx < 64 * 8 * 9; idx += 256) {
            int o = idx / 72;
            int rem = idx - o * 72;
            int cl = rem / 9;
            int tap = rem - cl * 9;
            wc_lds[o * 96 + cl * 12 + tap] =
                THETA * Wc[(size_t)(o * 64 + c0 + cl) * 9 + tap];
        }
        // ---- stage edge weights, prescaled by (1-theta), transposed ----
        for (int idx = tid; idx < 8 * 64; idx += 256) {
            int cl = idx >> 6;
            int o = idx & 63;
            we_lds[cl * 64 + o] = (1.0f - THETA) * We[o * 64 + c0 + cl];
        }
        __syncthreads();

        for (int cl = 0; cl < 8; ++cl) {
            // 6x6 input patch for this thread's 4x4 pixels (vector LDS reads)
            float p[6][6];
            #pragma unroll
            for (int rr = 0; rr < 6; ++rr) {
                const float* src = &x_lds[cl * 360 + (pr + rr) * 20 + pc];
                float4 v4 = *reinterpret_cast<const float4*>(src);
                float2 v2 = *reinterpret_cast<const float2*>(src + 4);
                p[rr][0] = v4.x; p[rr][1] = v4.y; p[rr][2] = v4.z; p[rr][3] = v4.w;
                p[rr][4] = v2.x; p[rr][5] = v2.y;
            }
            // |diff_v| = |x[y-1] - x[y+1]| at same column
            float adv[4][4];
            #pragma unroll
            for (int r = 0; r < 4; ++r)
                #pragma unroll
                for (int cc = 0; cc < 4; ++cc)
                    adv[r][cc] = fabsf(p[r][cc + 1] - p[r + 2][cc + 1]);

            float4 wev = *reinterpret_cast<const float4*>(&we_lds[cl * 64 + o0]);
            const float wea[4] = {wev.x, wev.y, wev.z, wev.w};

            #pragma unroll
            for (int oo = 0; oo < 4; ++oo) {
                const float* wp = &wc_lds[(o0 + oo) * 96 + cl * 12];
                float4 wa = *reinterpret_cast<const float4*>(wp);
                float4 wb = *reinterpret_cast<const float4*>(wp + 4);
                float w8 = wp[8];
                float we = wea[oo];
                #pragma unroll
                for (int r = 0; r < 4; ++r) {
                    #pragma unroll
                    for (int cc = 0; cc < 4; ++cc) {
                        float s = acc[oo][r * 4 + cc];
                        s += wa.x * p[r    ][cc    ];
                        s += wa.y * p[r    ][cc + 1];
                        s += wa.z * p[r    ][cc + 2];
                        s += wa.w * p[r + 1][cc    ];
                        s += wb.x * p[r + 1][cc + 1];
                        s += wb.y * p[r + 1][cc + 2];
                        s += wb.z * p[r + 2][cc    ];
                        s += wb.w * p[r + 2][cc + 1];
                        s += w8   * p[r + 2][cc + 2];
                        s += we   * adv[r][cc];
                        acc[oo][r * 4 + cc] = s;
                    }
                }
            }
        }
    }

    // ---- write combined (pre-attention) ----
    #pragma unroll
    for (int oo = 0; oo < 4; ++oo) {
        #pragma unroll
        for (int r = 0; r < 4; ++r) {
            float4 v = make_float4(acc[oo][r * 4 + 0], acc[oo][r * 4 + 1],
                                   acc[oo][r * 4 + 2], acc[oo][r * 4 + 3]);
            size_t off = (((size_t)b * 64 + o0 + oo) * 256 + (tileR + pr + r)) * 256
                         + (tileC + pc);
            *reinterpret_cast<float4*>(out + off) = v;
        }
    }

    // ---- block-level spatial-sum reduction, then one atomic per (b,o) ----
    __syncthreads();               // done reading x_lds; reuse as scratch
    float* red = x_lds;            // needs 64*16 floats
    #pragma unroll
    for (int oo = 0; oo < 4; ++oo) {
        float s = 0.f;
        #pragma unroll
        for (int p = 0; p < 16; ++p) s += acc[oo][p];
        red[(o0 + oo) * 16 + pg] = s;
    }
    __syncthreads();
    if (tid < 64) {
        float s = 0.f;
        #pragma unroll
        for (int g = 0; g < 16; ++g) s += red[tid * 16 + g];
        atomicAdd(&sums[b * 64 + tid], s);
    }
}

// Pass 2: tiny SE MLP: pooled -> relu(W1 p + b1) -> sigmoid(W2 h + b2)
__global__ __launch_bounds__(64) void cdc_attn_kernel(
    const float* __restrict__ sums,
    const float* __restrict__ W1, const float* __restrict__ b1,
    const float* __restrict__ W2, const float* __restrict__ b2,
    float* __restrict__ attn)
{
    __shared__ float pooled[512];
    __shared__ float hbuf[64];   // [b][r]
    const int tid = threadIdx.x;  // 64 threads
    const float inv = 1.0f / 65536.0f;
    for (int i = tid; i < 512; i += 64) pooled[i] = sums[i] * inv;
    __syncthreads();
    {
        int bb = tid >> 3, r = tid & 7;
        float s = b1[r];
        for (int o = 0; o < 64; ++o) s += W1[r * 64 + o] * pooled[bb * 64 + o];
        hbuf[bb * 8 + r] = fmaxf(s, 0.f);
    }
    __syncthreads();
    {
        int o = tid;
        for (int bb = 0; bb < 8; ++bb) {
            float z = b2[o];
            #pragma unroll
            for (int r = 0; r < 8; ++r) z += W2[o * 8 + r] * hbuf[bb * 8 + r];
            attn[bb * 64 + o] = 1.0f / (1.0f + expf(-z));
        }
    }
}

// Pass 3: in-place scale by attn[b,o], float4-vectorized.
__global__ __launch_bounds__(256) void cdc_scale_kernel(
    float* __restrict__ out, const float* __restrict__ attn)
{
    int i = blockIdx.x * 256 + threadIdx.x;       // one float4 per thread
    float4* o4 = reinterpret_cast<float4*>(out);
    float4 v = o4[i];
    int bo = i >> 14;                             // 65536/4 float4 per (b,o)
    float a = attn[bo];
    v.x *= a; v.y *= a; v.z *= a; v.w *= a;
    o4[i] = v;
}

extern "C" void kernel_launch(void* const* d_in, const int* in_sizes, int n_in,
                              void* d_out, int out_size, void* d_ws, size_t ws_size,
                              hipStream_t stream)
{
    const float* x  = (const float*)d_in[0];
    const float* Wc = (const float*)d_in[1];
    const float* bc = (const float*)d_in[2];
    const float* We = (const float*)d_in[3];
    const float* W1 = (const float*)d_in[4];
    const float* b1 = (const float*)d_in[5];
    const float* W2 = (const float*)d_in[6];
    const float* b2 = (const float*)d_in[7];
    float* out  = (float*)d_out;
    float* sums = (float*)d_ws;        // 512 floats
    float* attn = sums + 512;          // 512 floats

    hipMemsetAsync(sums, 0, 512 * sizeof(float), stream);

    dim3 grid1(16, 16, 8);             // (W tiles, H tiles, batch)
    cdc_main_kernel<<<grid1, 256, 0, stream>>>(x, Wc, bc, We, out, sums);
    cdc_attn_kernel<<<1, 64, 0, stream>>>(sums, W1, b1, W2, b2, attn);
    cdc_scale_kernel<<<32768, 256, 0, stream>>>(out, attn);
}

// Round 2
// 867.524 us; speedup vs baseline: 1.1999x; 1.1999x over previous
//
#include <hip/hip_runtime.h>
#include <math.h>

#define THETA 0.7f

// Pass 1: fused 3x3 conv + vertical-diff edge conv + combine, plus per-(b,o)
// spatial-sum accumulation for the SE pooling.
// Block: one batch, 16x16 pixel tile, all 64 output channels.
// Thread: 4 output channels x (4x4 pixels) = 64 fp32 accumulators.
//
// LDS layouts chosen for bank behavior (wave = 64 lanes, 32 banks):
//  - wc_lds[cl][tap][o]: lane reads float4 at addr stride 16 B over o0=4k ->
//    banks 4k%32, 2-way aliasing only (free). The previous [o][cl][tap] layout
//    had 384 B per-lane stride -> 16-way conflicts (3.2e8 conflict cycles).
//  - x_lds patch reads: 4 distinct b128 addrs/wave (16-lane broadcast) -> free.
__global__ __launch_bounds__(256) void cdc_main_kernel(
    const float* __restrict__ x, const float* __restrict__ Wc,
    const float* __restrict__ bc, const float* __restrict__ We,
    float* __restrict__ out, float* __restrict__ sums)
{
    __shared__ float x_lds[8 * 18 * 20];   // [c_local][row(18)][stride 20]
    __shared__ float wc_lds[8 * 9 * 64];   // [c_local][tap][o]  (theta-prescaled)
    __shared__ float we_lds[8 * 64];       // [c_local][o] ((1-theta)-prescaled)

    const int tid = threadIdx.x;
    const int tileC = blockIdx.x * 16;
    const int tileR = blockIdx.y * 16;
    const int b = blockIdx.z;

    const int o0 = (tid & 15) * 4;      // 4 consecutive output channels
    const int pg = tid >> 4;            // pixel group 0..15
    const int pr = (pg >> 2) * 4;       // sub-tile row offset
    const int pc = (pg & 3) * 4;        // sub-tile col offset

    float acc[4][16];
    #pragma unroll
    for (int oo = 0; oo < 4; ++oo) {
        float init = THETA * bc[o0 + oo];   // bias folded in, prescaled
        #pragma unroll
        for (int p = 0; p < 16; ++p) acc[oo][p] = init;
    }

    for (int chunk = 0; chunk < 8; ++chunk) {
        const int c0 = chunk * 8;
        __syncthreads();   // previous iteration's compute done before restage
        // ---- stage x tile (18x18 with halo, zero-padded at borders) ----
        for (int idx = tid; idx < 8 * 18 * 18; idx += 256) {
            int c = idx / 324;
            int rem = idx - c * 324;
            int r = rem / 18;
            int col = rem - r * 18;
            int gr = tileR + r - 1;
            int gc = tileC + col - 1;
            float v = 0.f;
            if (gr >= 0 && gr < 256 && gc >= 0 && gc < 256)
                v = x[(((size_t)b * 64 + c0 + c) * 256 + gr) * 256 + gc];
            x_lds[c * 360 + r * 20 + col] = v;
        }
        // ---- stage conv weights [cl][tap][o], prescaled by theta ----
        for (int idx = tid; idx < 8 * 9 * 64; idx += 256) {
            int ct = idx >> 6;              // cl*9 + tap
            int o  = idx & 63;
            int cl = ct / 9;
            int tap = ct - cl * 9;
            wc_lds[ct * 64 + o] =
                THETA * Wc[(size_t)o * 576 + (size_t)(c0 + cl) * 9 + tap];
        }
        // ---- stage edge weights, prescaled by (1-theta), transposed ----
        for (int idx = tid; idx < 8 * 64; idx += 256) {
            int cl = idx >> 6;
            int o = idx & 63;
            we_lds[cl * 64 + o] = (1.0f - THETA) * We[o * 64 + c0 + cl];
        }
        __syncthreads();

        for (int cl = 0; cl < 8; ++cl) {
            // 6x6 input patch for this thread's 4x4 pixels (vector LDS reads)
            float p[6][6];
            #pragma unroll
            for (int rr = 0; rr < 6; ++rr) {
                const float* src = &x_lds[cl * 360 + (pr + rr) * 20 + pc];
                float4 v4 = *reinterpret_cast<const float4*>(src);
                float2 v2 = *reinterpret_cast<const float2*>(src + 4);
                p[rr][0] = v4.x; p[rr][1] = v4.y; p[rr][2] = v4.z; p[rr][3] = v4.w;
                p[rr][4] = v2.x; p[rr][5] = v2.y;
            }
            // |diff_v| = |x[y-1] - x[y+1]| at same column
            float adv[4][4];
            #pragma unroll
            for (int r = 0; r < 4; ++r)
                #pragma unroll
                for (int cc = 0; cc < 4; ++cc)
                    adv[r][cc] = fabsf(p[r][cc + 1] - p[r + 2][cc + 1]);

            float4 wev = *reinterpret_cast<const float4*>(&we_lds[cl * 64 + o0]);
            const float wea[4] = {wev.x, wev.y, wev.z, wev.w};

            // 9 taps x 4 output channels, conflict-free float4 reads
            float wts[9][4];
            #pragma unroll
            for (int t = 0; t < 9; ++t) {
                float4 w4 = *reinterpret_cast<const float4*>(
                    &wc_lds[(cl * 9 + t) * 64 + o0]);
                wts[t][0] = w4.x; wts[t][1] = w4.y;
                wts[t][2] = w4.z; wts[t][3] = w4.w;
            }

            #pragma unroll
            for (int oo = 0; oo < 4; ++oo) {
                float we = wea[oo];
                #pragma unroll
                for (int r = 0; r < 4; ++r) {
                    #pragma unroll
                    for (int cc = 0; cc < 4; ++cc) {
                        float s = acc[oo][r * 4 + cc];
                        s += wts[0][oo] * p[r    ][cc    ];
                        s += wts[1][oo] * p[r    ][cc + 1];
                        s += wts[2][oo] * p[r    ][cc + 2];
                        s += wts[3][oo] * p[r + 1][cc    ];
                        s += wts[4][oo] * p[r + 1][cc + 1];
                        s += wts[5][oo] * p[r + 1][cc + 2];
                        s += wts[6][oo] * p[r + 2][cc    ];
                        s += wts[7][oo] * p[r + 2][cc + 1];
                        s += wts[8][oo] * p[r + 2][cc + 2];
                        s += we * adv[r][cc];
                        acc[oo][r * 4 + cc] = s;
                    }
                }
            }
        }
    }

    // ---- write combined (pre-attention) ----
    #pragma unroll
    for (int oo = 0; oo < 4; ++oo) {
        #pragma unroll
        for (int r = 0; r < 4; ++r) {
            float4 v = make_float4(acc[oo][r * 4 + 0], acc[oo][r * 4 + 1],
                                   acc[oo][r * 4 + 2], acc[oo][r * 4 + 3]);
            size_t off = (((size_t)b * 64 + o0 + oo) * 256 + (tileR + pr + r)) * 256
                         + (tileC + pc);
            *reinterpret_cast<float4*>(out + off) = v;
        }
    }

    // ---- block-level spatial-sum reduction, then one atomic per (b,o) ----
    __syncthreads();               // done reading x_lds; reuse as scratch
    float* red = x_lds;            // needs 16*64 floats; layout [pg][o] (2-way max)
    #pragma unroll
    for (int oo = 0; oo < 4; ++oo) {
        float s = 0.f;
        #pragma unroll
        for (int p = 0; p < 16; ++p) s += acc[oo][p];
        red[pg * 64 + o0 + oo] = s;
    }
    __syncthreads();
    if (tid < 64) {
        float s = 0.f;
        #pragma unroll
        for (int g = 0; g < 16; ++g) s += red[g * 64 + tid];
        atomicAdd(&sums[b * 64 + tid], s);
    }
}

// Pass 2: tiny SE MLP: pooled -> relu(W1 p + b1) -> sigmoid(W2 h + b2)
__global__ __launch_bounds__(64) void cdc_attn_kernel(
    const float* __restrict__ sums,
    const float* __restrict__ W1, const float* __restrict__ b1,
    const float* __restrict__ W2, const float* __restrict__ b2,
    float* __restrict__ attn)
{
    __shared__ float pooled[512];
    __shared__ float hbuf[64];   // [b][r]
    const int tid = threadIdx.x;  // 64 threads
    const float inv = 1.0f / 65536.0f;
    for (int i = tid; i < 512; i += 64) pooled[i] = sums[i] * inv;
    __syncthreads();
    {
        int bb = tid >> 3, r = tid & 7;
        float s = b1[r];
        for (int o = 0; o < 64; ++o) s += W1[r * 64 + o] * pooled[bb * 64 + o];
        hbuf[bb * 8 + r] = fmaxf(s, 0.f);
    }
    __syncthreads();
    {
        int o = tid;
        for (int bb = 0; bb < 8; ++bb) {
            float z = b2[o];
            #pragma unroll
            for (int r = 0; r < 8; ++r) z += W2[o * 8 + r] * hbuf[bb * 8 + r];
            attn[bb * 64 + o] = 1.0f / (1.0f + expf(-z));
        }
    }
}

// Pass 3: in-place scale by attn[b,o], float4-vectorized.
__global__ __launch_bounds__(256) void cdc_scale_kernel(
    float* __restrict__ out, const float* __restrict__ attn)
{
    int i = blockIdx.x * 256 + threadIdx.x;       // one float4 per thread
    float4* o4 = reinterpret_cast<float4*>(out);
    float4 v = o4[i];
    int bo = i >> 14;                             // 65536/4 float4 per (b,o)
    float a = attn[bo];
    v.x *= a; v.y *= a; v.z *= a; v.w *= a;
    o4[i] = v;
}

extern "C" void kernel_launch(void* const* d_in, const int* in_sizes, int n_in,
                              void* d_out, int out_size, void* d_ws, size_t ws_size,
                              hipStream_t stream)
{
    const float* x  = (const float*)d_in[0];
    const float* Wc = (const float*)d_in[1];
    const float* bc = (const float*)d_in[2];
    const float* We = (const float*)d_in[3];
    const float* W1 = (const float*)d_in[4];
    const float* b1 = (const float*)d_in[5];
    const float* W2 = (const float*)d_in[6];
    const float* b2 = (const float*)d_in[7];
    float* out  = (float*)d_out;
    float* sums = (float*)d_ws;        // 512 floats
    float* attn = sums + 512;          // 512 floats

    hipMemsetAsync(sums, 0, 512 * sizeof(float), stream);

    dim3 grid1(16, 16, 8);             // (W tiles, H tiles, batch)
    cdc_main_kernel<<<grid1, 256, 0, stream>>>(x, Wc, bc, We, out, sums);
    cdc_attn_kernel<<<1, 64, 0, stream>>>(sums, W1, b1, W2, b2, attn);
    cdc_scale_kernel<<<32768, 256, 0, stream>>>(out, attn);
}

// Round 3
// 353.231 us; speedup vs baseline: 2.9470x; 2.4560x over previous
//
#include <hip/hip_runtime.h>
#include <hip/hip_bf16.h>
#include <math.h>

#define THETA 0.7f

typedef short short8 __attribute__((ext_vector_type(8)));
typedef float floatx4 __attribute__((ext_vector_type(4)));

__device__ __forceinline__ unsigned short f2bu(float f) {
    return __builtin_bit_cast(unsigned short, __float2bfloat16(f));
}
__device__ __forceinline__ float b2f(unsigned short u) {
    unsigned v = ((unsigned)u) << 16;
    return __builtin_bit_cast(float, v);
}

// Weight prep: fused bf16 weight matrix Bw[2 chunks][64 n][328 k].
// Per chunk (32 input channels): k = tap*32 + c_l (theta*Wc), k = 288+c_l
// ((1-theta)*We), k >= 320 zero pad.
__global__ void cdc_prep(const float* __restrict__ Wc,
                         const float* __restrict__ We,
                         unsigned short* __restrict__ Bw)
{
    int idx = blockIdx.x * 256 + threadIdx.x;
    if (idx >= 2 * 64 * 328) return;
    int k = idx % 328;
    int n = (idx / 328) & 63;
    int chunk = idx / 20992;
    int c0 = chunk << 5;
    float v = 0.f;
    if (k < 288) {
        int tap = k >> 5, cl = k & 31;
        v = THETA * Wc[n * 576 + (c0 + cl) * 9 + tap];
    } else if (k < 320) {
        int cl = k - 288;
        v = (1.0f - THETA) * We[n * 64 + c0 + cl];
    }
    Bw[idx] = f2bu(v);
}

// Main: implicit-GEMM via 16x16x32 bf16 MFMA.
// Block = 16x16 pixel tile x all 64 oc. Wave w: rows 4w..4w+3 (4 M-frags),
// all 4 N-frags. K = 2 chunks x (9 conv ksteps + 1 edge kstep).
// LDS x-tile [18 rows][22 cols][40 c] bf16 (c innermost -> A-frag is one
// b128; col stride 80 B -> 2-way banks on reads).
__global__ __launch_bounds__(256, 2) void cdc_main_kernel(
    const float* __restrict__ x, const unsigned short* __restrict__ Bw,
    const float* __restrict__ bc, float* __restrict__ out,
    float* __restrict__ sums)
{
    __shared__ unsigned short xs[18 * 22 * 40];   // 31680 B
    __shared__ unsigned short bs[64 * 328];       // 41984 B  [n][k]

    const int tid  = threadIdx.x;
    const int lane = tid & 63;
    const int w    = tid >> 6;
    const int m    = lane & 15;   // A: pixel-in-frag (image col); B/D: oc-in-frag
    const int q    = lane >> 4;   // k-subchunk quad

    const int tile = blockIdx.x;
    const int b    = tile >> 8;
    const int trow = ((tile >> 4) & 15) << 4;
    const int tcol = (tile & 15) << 4;

    floatx4 acc[4][4];   // [mf][nf]; D: col=lane&15 (oc), row=q*4+reg (img col)
    #pragma unroll
    for (int nf = 0; nf < 4; ++nf) {
        float bias = THETA * bc[nf * 16 + m];
        #pragma unroll
        for (int mf = 0; mf < 4; ++mf)
            acc[mf][nf] = (floatx4){bias, bias, bias, bias};
    }

    for (int chunk = 0; chunk < 2; ++chunk) {
        const int c0 = chunk << 5;
        __syncthreads();
        // ---- stage Bw chunk (linear 16 B copy) ----
        {
            const ulonglong2* src = (const ulonglong2*)(Bw + chunk * 20992);
            ulonglong2* dst = (ulonglong2*)bs;
            for (int i = tid; i < 2624; i += 256) dst[i] = src[i];
        }
        // ---- stage x chunk: 4x4 (col x c) transpose blocks, f32->bf16 ----
        for (int bi = tid; bi < 720; bi += 256) {
            const int cgrp = bi / 90;           // 0..7 (4 c each)
            const int rem  = bi - cgrp * 90;
            const int row  = rem / 5;           // 0..17 (halo rows)
            const int cg   = rem - row * 5;     // 0..4  (4 cols each)
            const int gr   = trow + row - 1;
            const int gc0  = tcol + (cg << 2) - 1;
            float v[4][4];
            const bool rok = (unsigned)gr < 256u;
            const float* xb = x + (((size_t)(b * 64 + c0 + cgrp * 4)) * 256 +
                                   (rok ? gr : 0)) * 256;
            if (rok && gc0 >= 0 && gc0 + 3 < 256) {
                #pragma unroll
                for (int i = 0; i < 4; ++i) {
                    float4 t = *(const float4*)(xb + (size_t)i * 65536 + gc0);
                    v[i][0] = t.x; v[i][1] = t.y; v[i][2] = t.z; v[i][3] = t.w;
                }
            } else {
                #pragma unroll
                for (int i = 0; i < 4; ++i)
                    #pragma unroll
                    for (int e = 0; e < 4; ++e) {
                        int gc = gc0 + e;
                        v[i][e] = (rok && (unsigned)gc < 256u)
                                  ? xb[(size_t)i * 65536 + gc] : 0.f;
                    }
            }
            unsigned short* dst = &xs[(row * 22 + (cg << 2)) * 40 + (cgrp << 2)];
            #pragma unroll
            for (int e = 0; e < 4; ++e) {
                unsigned long long d =
                      (unsigned long long)f2bu(v[0][e])
                    | ((unsigned long long)f2bu(v[1][e]) << 16)
                    | ((unsigned long long)f2bu(v[2][e]) << 32)
                    | ((unsigned long long)f2bu(v[3][e]) << 48);
                *(unsigned long long*)(dst + e * 40) = d;
            }
        }
        __syncthreads();

        // ---- 9 conv ksteps (one tap x 32 channels each) ----
        #pragma unroll
        for (int tap = 0; tap < 9; ++tap) {
            const int dy = tap / 3, dx = tap % 3;
            short8 bf[4];
            #pragma unroll
            for (int nf = 0; nf < 4; ++nf)
                bf[nf] = *(const short8*)
                    &bs[(nf * 16 + m) * 328 + tap * 32 + q * 8];
            #pragma unroll
            for (int mf = 0; mf < 4; ++mf) {
                const short8 af = *(const short8*)
                    &xs[((w * 4 + mf + dy) * 22 + (m + dx)) * 40 + q * 8];
                #pragma unroll
                for (int nf = 0; nf < 4; ++nf)
                    acc[mf][nf] = __builtin_amdgcn_mfma_f32_16x16x32_bf16(
                        af, bf[nf], acc[mf][nf], 0, 0, 0);
            }
        }
        // ---- edge kstep: A = |x(r-1) - x(r+1)| over 32 channels ----
        {
            short8 bf[4];
            #pragma unroll
            for (int nf = 0; nf < 4; ++nf)
                bf[nf] = *(const short8*)&bs[(nf * 16 + m) * 328 + 288 + q * 8];
            #pragma unroll
            for (int mf = 0; mf < 4; ++mf) {
                const short8 a0 = *(const short8*)
                    &xs[((w * 4 + mf) * 22 + m + 1) * 40 + q * 8];
                const short8 a1 = *(const short8*)
                    &xs[((w * 4 + mf + 2) * 22 + m + 1) * 40 + q * 8];
                short8 af;
                #pragma unroll
                for (int j = 0; j < 8; ++j)
                    af[j] = (short)f2bu(fabsf(
                        b2f((unsigned short)a0[j]) - b2f((unsigned short)a1[j])));
                #pragma unroll
                for (int nf = 0; nf < 4; ++nf)
                    acc[mf][nf] = __builtin_amdgcn_mfma_f32_16x16x32_bf16(
                        af, bf[nf], acc[mf][nf], 0, 0, 0);
            }
        }
    }

    // ---- write combined (pre-attention), float4 per (frag, lane) ----
    #pragma unroll
    for (int mf = 0; mf < 4; ++mf) {
        const int y = trow + w * 4 + mf;
        #pragma unroll
        for (int nf = 0; nf < 4; ++nf) {
            const int oc = nf * 16 + m;
            size_t off = (((size_t)(b * 64 + oc)) * 256 + y) * 256 + tcol + q * 4;
            float4 val = make_float4(acc[mf][nf][0], acc[mf][nf][1],
                                     acc[mf][nf][2], acc[mf][nf][3]);
            *(float4*)(out + off) = val;
        }
    }

    // ---- GAP partial sums -> one atomic per (b,oc) ----
    float p[4];
    #pragma unroll
    for (int nf = 0; nf < 4; ++nf) {
        float s = 0.f;
        #pragma unroll
        for (int mf = 0; mf < 4; ++mf)
            s += acc[mf][nf][0] + acc[mf][nf][1] + acc[mf][nf][2] + acc[mf][nf][3];
        s += __shfl_xor(s, 32);
        s += __shfl_xor(s, 16);    // quads share oc; lanes 0..15 hold quad-sum
        p[nf] = s;
    }
    __syncthreads();                       // xs no longer needed
    float* red = (float*)xs;               // [4 waves][64 oc]
    if (q == 0) {
        #pragma unroll
        for (int nf = 0; nf < 4; ++nf) red[w * 64 + nf * 16 + m] = p[nf];
    }
    __syncthreads();
    if (tid < 64) {
        float s = red[tid] + red[64 + tid] + red[128 + tid] + red[192 + tid];
        atomicAdd(&sums[b * 64 + tid], s);
    }
}

// SE MLP: pooled -> relu(W1 p + b1) -> sigmoid(W2 h + b2)
__global__ __launch_bounds__(64) void cdc_attn_kernel(
    const float* __restrict__ sums,
    const float* __restrict__ W1, const float* __restrict__ b1,
    const float* __restrict__ W2, const float* __restrict__ b2,
    float* __restrict__ attn)
{
    __shared__ float pooled[512];
    __shared__ float hbuf[64];
    const int tid = threadIdx.x;
    const float inv = 1.0f / 65536.0f;
    for (int i = tid; i < 512; i += 64) pooled[i] = sums[i] * inv;
    __syncthreads();
    {
        int bb = tid >> 3, r = tid & 7;
        float s = b1[r];
        for (int o = 0; o < 64; ++o) s += W1[r * 64 + o] * pooled[bb * 64 + o];
        hbuf[bb * 8 + r] = fmaxf(s, 0.f);
    }
    __syncthreads();
    {
        int o = tid;
        for (int bb = 0; bb < 8; ++bb) {
            float z = b2[o];
            #pragma unroll
            for (int r = 0; r < 8; ++r) z += W2[o * 8 + r] * hbuf[bb * 8 + r];
            attn[bb * 64 + o] = 1.0f / (1.0f + expf(-z));
        }
    }
}

// In-place scale by attn[b,o], float4-vectorized.
__global__ __launch_bounds__(256) void cdc_scale_kernel(
    float* __restrict__ out, const float* __restrict__ attn)
{
    int i = blockIdx.x * 256 + threadIdx.x;
    float4* o4 = reinterpret_cast<float4*>(out);
    float4 v = o4[i];
    float a = attn[i >> 14];
    v.x *= a; v.y *= a; v.z *= a; v.w *= a;
    o4[i] = v;
}

extern "C" void kernel_launch(void* const* d_in, const int* in_sizes, int n_in,
                              void* d_out, int out_size, void* d_ws, size_t ws_size,
                              hipStream_t stream)
{
    const float* x  = (const float*)d_in[0];
    const float* Wc = (const float*)d_in[1];
    const float* bc = (const float*)d_in[2];
    const float* We = (const float*)d_in[3];
    const float* W1 = (const float*)d_in[4];
    const float* b1 = (const float*)d_in[5];
    const float* W2 = (const float*)d_in[6];
    const float* b2 = (const float*)d_in[7];
    float* out  = (float*)d_out;

    float* sums = (float*)d_ws;                        // 512 f32
    float* attn = sums + 512;                          // 512 f32
    unsigned short* Bw = (unsigned short*)(attn + 512); // 41984 bf16 (16B-aligned)

    hipMemsetAsync(sums, 0, 512 * sizeof(float), stream);
    cdc_prep<<<164, 256, 0, stream>>>(Wc, We, Bw);
    cdc_main_kernel<<<2048, 256, 0, stream>>>(x, Bw, bc, out, sums);
    cdc_attn_kernel<<<1, 64, 0, stream>>>(sums, W1, b1, W2, b2, attn);
    cdc_scale_kernel<<<32768, 256, 0, stream>>>(out, attn);
}